// Round 6
// baseline (96.436 us; speedup 1.0000x reference)
//
#include <hip/hip_runtime.h>
#include <hip/hip_bf16.h>
#include <math.h>

// out = squash(ConvTranspose2d(x)+bias); routing loop is identity (R0 analysis).
// GEMM per parity class (ph,pw): out[px,co] = bias + sum_{tap in class} X·W_tap
// bf16 MFMA 16x16x32. Class taps: (0,0)->1, (0,1)/(1,0)->2, (1,1)->4.
//
// R6: B staged in LDS (32 KB/block, one barrier), K-loop = 2 A global loads +
// NT ds_read_b128 + 2*NT MFMA per step. Grid rebalanced so every block does
// TAPS*NT = 8 tap-tiles (64 MFMA/wave) with exactly 32 KB LDS:
//   bx=0: class(0,0) all 8 co-tiles; bx=1..4: classes (0,1),(1,0) co-halves;
//   bx=5..8: class(1,1) co-quarters.  Grid 9 x 8(q) x 16(b) = 1152 blocks.
//
// ws: [0,4MB)   xbf bf16 [16][8][32][32][16] (x strides /2B)
//     [4MB,..)  Wl  bf16 [9][4][8][64][8] (tap,s,t,lane,j); B[n=lane&15][k=quad*8+j],
//               co = t*16+n, ci = s*32+quad*8+j.

typedef __attribute__((ext_vector_type(8))) __bf16 bf16x8;
typedef __attribute__((ext_vector_type(4))) float f32x4;

#define XBF_ELEMS (16 * 8 * 32 * 32 * 16)  // 2097152

__global__ __launch_bounds__(256) void prep(const float* __restrict__ x,
                                            const float* __restrict__ w,
                                            __hip_bfloat16* __restrict__ xbf,
                                            __hip_bfloat16* __restrict__ wl) {
    const int bx = blockIdx.x;
    if (bx < 1024) {  // x -> bf16, 8 elems/thread
        const int i = (bx * 256 + threadIdx.x) * 8;
        float4 a = *(const float4*)(x + i);
        float4 b = *(const float4*)(x + i + 4);
        union { bf16x8 v; __hip_bfloat162 h[4]; } u;
        u.h[0] = __float22bfloat162_rn(make_float2(a.x, a.y));
        u.h[1] = __float22bfloat162_rn(make_float2(a.z, a.w));
        u.h[2] = __float22bfloat162_rn(make_float2(b.x, b.y));
        u.h[3] = __float22bfloat162_rn(make_float2(b.z, b.w));
        *(bf16x8*)(xbf + i) = u.v;
    } else {          // w -> fragment-linear bf16
        const int idx = (bx - 1024) * 256 + threadIdx.x;  // = ci*1152+co*9+tap
        const int ci  = idx / 1152;
        const int rem = idx - ci * 1152;
        const int co  = rem / 9;
        const int tap = rem - co * 9;
        const int s = ci >> 5, quad = (ci >> 3) & 3, j = ci & 7;
        const int t = co >> 4, n16 = co & 15;
        const int dst = ((((tap * 4 + s) * 8 + t) * 64) + quad * 16 + n16) * 8 + j;
        wl[dst] = __float2bfloat16(w[idx]);
    }
}

template <int PH, int PW, int NT>
__device__ __forceinline__ void caps_body(
    const __hip_bfloat16* __restrict__ xbf, const __hip_bfloat16* __restrict__ wl,
    const float* __restrict__ bias, float* __restrict__ out,
    __hip_bfloat16* bsh, int t0)
{
    constexpr int NH = PH ? 2 : 1, NW = PW ? 2 : 1;
    constexpr int CHE = NT * 512;   // elems per (tap,s) chunk
    const int tid = threadIdx.x, lane = tid & 63, wv = tid >> 6;
    const int q = blockIdx.y, b = blockIdx.z;

    // ---- stage B slice into LDS: 16384 bf16 = 32 KB, fully coalesced ----
    #pragma unroll
    for (int it = 0; it < 8; ++it) {
        const int idx    = it * 2048 + tid * 8;
        const int c2     = idx / CHE;         // (ti*4 + s)
        const int within = idx % CHE;
        const int s  = c2 & 3, ti = c2 >> 2;
        const int kh = PH ? (ti / NW) * 2 : 1;
        const int kw = PW ? (ti % NW) * 2 : 1;
        const int tap = kh * 3 + kw;
        *(bf16x8*)(bsh + idx) =
            *(const bf16x8*)(wl + ((tap * 4 + s) * 8 + t0) * 512 + within);
    }
    __syncthreads();

    const int rp = wv >> 1, chf = wv & 1;
    const int rw0 = q * 4 + rp * 2;       // class rows rw0, rw0+1 (oh = 2*rw+PH)
    const int n16  = lane & 15;
    const int quad = lane >> 4;
    const int c    = chf * 16 + n16;      // class col (ow = 2*c + PW)

    float bb[NT];
    #pragma unroll
    for (int tt = 0; tt < NT; ++tt) bb[tt] = bias[(t0 + tt) * 16 + n16];

    // A-frag: A[m=n16][k=quad*8+j] = xbf[b, 2s+(quad>>1), ih, iw, (quad&1)*8+j]
    const __hip_bfloat16* xq = xbf + b * 131072 + (quad >> 1) * 16384 + (quad & 1) * 8;

    f32x4 acc[2][NT];
    #pragma unroll
    for (int r = 0; r < 2; ++r)
        #pragma unroll
        for (int tt = 0; tt < NT; ++tt) acc[r][tt] = (f32x4){0.f, 0.f, 0.f, 0.f};

    #pragma unroll
    for (int khi = 0; khi < NH; ++khi) {
        const int dh = PH ? (1 - khi) : 0;
        const int ih0 = rw0 + dh, ih1 = ih0 + 1;
        const bool v0 = (ih0 < 32), v1 = (ih1 < 32);      // wave-uniform
        const int ih0c = v0 ? ih0 : 31, ih1c = v1 ? ih1 : 31;
        #pragma unroll
        for (int kwi = 0; kwi < NW; ++kwi) {
            const int dw = PW ? (1 - kwi) : 0;
            const int iw = c + dw;
            const bool vw = (iw < 32);                    // per-lane
            const int iwc = vw ? iw : 31;
            const int ti = khi * NW + kwi;
            const __hip_bfloat16* a0p = xq + ih0c * 512 + iwc * 16;
            const __hip_bfloat16* a1p = xq + ih1c * 512 + iwc * 16;
            const __hip_bfloat16* wb  = bsh + ti * (4 * CHE) + lane * 8;
            #pragma unroll
            for (int s = 0; s < 4; ++s) {
                bf16x8 a0 = *(const bf16x8*)(a0p + s * 32768);
                bf16x8 a1 = *(const bf16x8*)(a1p + s * 32768);
                if (!(v0 && vw)) a0 = (bf16x8){};
                if (!(v1 && vw)) a1 = (bf16x8){};
                #pragma unroll
                for (int tt = 0; tt < NT; ++tt) {
                    bf16x8 bf = *(const bf16x8*)(wb + s * CHE + tt * 512);
                    acc[0][tt] = __builtin_amdgcn_mfma_f32_16x16x32_bf16(a0, bf, acc[0][tt], 0, 0, 0);
                    acc[1][tt] = __builtin_amdgcn_mfma_f32_16x16x32_bf16(a1, bf, acc[1][tt], 0, 0, 0);
                }
            }
        }
    }

    // Epilogue: +bias, squash over d (16 lanes of each quad), nontemporal store.
    // C/D: d = n16, pixel row p = quad*4 + reg -> ow = 2*(chf*16+p) + PW.
    #pragma unroll
    for (int row = 0; row < 2; ++row) {
        const int oh = (rw0 + row) * 2 + PH;
        float y[NT][4], sq[NT][4];
        #pragma unroll
        for (int tt = 0; tt < NT; ++tt)
            #pragma unroll
            for (int r = 0; r < 4; ++r) {
                y[tt][r]  = acc[row][tt][r] + bb[tt];
                sq[tt][r] = y[tt][r] * y[tt][r];
            }
        #pragma unroll
        for (int st = 1; st <= 8; st <<= 1)
            #pragma unroll
            for (int tt = 0; tt < NT; ++tt)
                #pragma unroll
                for (int r = 0; r < 4; ++r)
                    sq[tt][r] += __shfl_xor(sq[tt][r], st, 64);
        #pragma unroll
        for (int tt = 0; tt < NT; ++tt)
            #pragma unroll
            for (int r = 0; r < 4; ++r) {
                const float s2 = sq[tt][r];
                const float f  = s2 / ((1.f + s2) * sqrtf(s2 + 1e-7f));
                const int ow = (chf * 16 + quad * 4 + r) * 2 + PW;
                __builtin_nontemporal_store(
                    y[tt][r] * f,
                    out + (((b * 8 + t0 + tt) * 64 + oh) * 64 + ow) * 16 + n16);
            }
    }
}

__global__ __launch_bounds__(256, 4) void caps_mfma(
    const __hip_bfloat16* __restrict__ xbf, const __hip_bfloat16* __restrict__ wl,
    const float* __restrict__ bias, float* __restrict__ out)
{
    __shared__ __hip_bfloat16 bsh[16384];  // 32 KB, uniform across variants
    const int bx = blockIdx.x;             // 9 balanced variants (64 MFMA/wave)
    if      (bx == 0) caps_body<0, 0, 8>(xbf, wl, bias, out, bsh, 0);
    else if (bx <  3) caps_body<0, 1, 4>(xbf, wl, bias, out, bsh, (bx - 1) * 4);
    else if (bx <  5) caps_body<1, 0, 4>(xbf, wl, bias, out, bsh, (bx - 3) * 4);
    else              caps_body<1, 1, 2>(xbf, wl, bias, out, bsh, (bx - 5) * 2);
}

extern "C" void kernel_launch(void* const* d_in, const int* in_sizes, int n_in,
                              void* d_out, int out_size, void* d_ws, size_t ws_size,
                              hipStream_t stream) {
    const float* x    = (const float*)d_in[0];
    const float* wgt  = (const float*)d_in[1];
    const float* bias = (const float*)d_in[2];
    float* out = (float*)d_out;

    __hip_bfloat16* xbf = (__hip_bfloat16*)d_ws;
    __hip_bfloat16* wlb = xbf + XBF_ELEMS;

    prep<<<1024 + 576, 256, 0, stream>>>(x, wgt, xbf, wlb);
    caps_mfma<<<dim3(9, 8, 16), 256, 0, stream>>>(xbf, wlb, bias, out);
}

// Round 7
// 93.001 us; speedup vs baseline: 1.0369x; 1.0369x over previous
//
#include <hip/hip_runtime.h>
#include <hip/hip_bf16.h>
#include <math.h>

// out = squash(ConvTranspose2d(x)+bias); routing loop is identity (R0 analysis).
// GEMM per parity class (ph,pw): out[px,co] = bias + sum_{tap in class} X·W_tap
// bf16 MFMA 16x16x32. Class taps: (0,0)->1, (0,1)/(1,0)->2, (1,1)->4.
//
// R7: squash reduction over d (16 lanes) moved from __shfl_xor (LDS pipe,
// ~27K cyc/CU serialized) to DPP butterfly on VALU: xor1/xor2 via quad_perm,
// then row_half_mirror + row_mirror. Rest identical to R6 (balanced 9-variant
// grid, 32 KB LDS B-stage, 64 MFMA/wave).
//
// ws: [0,4MB)   xbf bf16 [16][8][32][32][16] (x strides /2B)
//     [4MB,..)  Wl  bf16 [9][4][8][64][8] (tap,s,t,lane,j); B[n=lane&15][k=quad*8+j],
//               co = t*16+n, ci = s*32+quad*8+j.

typedef __attribute__((ext_vector_type(8))) __bf16 bf16x8;
typedef __attribute__((ext_vector_type(4))) float f32x4;

#define XBF_ELEMS (16 * 8 * 32 * 32 * 16)  // 2097152

__global__ __launch_bounds__(256) void prep(const float* __restrict__ x,
                                            const float* __restrict__ w,
                                            __hip_bfloat16* __restrict__ xbf,
                                            __hip_bfloat16* __restrict__ wl) {
    const int bx = blockIdx.x;
    if (bx < 1024) {  // x -> bf16, 8 elems/thread
        const int i = (bx * 256 + threadIdx.x) * 8;
        float4 a = *(const float4*)(x + i);
        float4 b = *(const float4*)(x + i + 4);
        union { bf16x8 v; __hip_bfloat162 h[4]; } u;
        u.h[0] = __float22bfloat162_rn(make_float2(a.x, a.y));
        u.h[1] = __float22bfloat162_rn(make_float2(a.z, a.w));
        u.h[2] = __float22bfloat162_rn(make_float2(b.x, b.y));
        u.h[3] = __float22bfloat162_rn(make_float2(b.z, b.w));
        *(bf16x8*)(xbf + i) = u.v;
    } else {          // w -> fragment-linear bf16
        const int idx = (bx - 1024) * 256 + threadIdx.x;  // = ci*1152+co*9+tap
        const int ci  = idx / 1152;
        const int rem = idx - ci * 1152;
        const int co  = rem / 9;
        const int tap = rem - co * 9;
        const int s = ci >> 5, quad = (ci >> 3) & 3, j = ci & 7;
        const int t = co >> 4, n16 = co & 15;
        const int dst = ((((tap * 4 + s) * 8 + t) * 64) + quad * 16 + n16) * 8 + j;
        wl[dst] = __float2bfloat16(w[idx]);
    }
}

// DPP butterfly add within each 16-lane row (VALU pipe, not LDS).
template <int CTRL>
__device__ __forceinline__ float dpp_xadd(float v) {
    int p = __builtin_amdgcn_update_dpp(0, __float_as_int(v), CTRL, 0xF, 0xF, true);
    return v + __int_as_float(p);
}
__device__ __forceinline__ float rowsum16(float v) {
    v = dpp_xadd<0xB1>(v);    // quad_perm [1,0,3,2]  : xor 1
    v = dpp_xadd<0x4E>(v);    // quad_perm [2,3,0,1]  : xor 2
    v = dpp_xadd<0x141>(v);   // row_half_mirror      : combine 4s
    v = dpp_xadd<0x140>(v);   // row_mirror           : combine 8s
    return v;
}

template <int PH, int PW, int NT>
__device__ __forceinline__ void caps_body(
    const __hip_bfloat16* __restrict__ xbf, const __hip_bfloat16* __restrict__ wl,
    const float* __restrict__ bias, float* __restrict__ out,
    __hip_bfloat16* bsh, int t0)
{
    constexpr int NH = PH ? 2 : 1, NW = PW ? 2 : 1;
    constexpr int CHE = NT * 512;   // elems per (tap,s) chunk
    const int tid = threadIdx.x, lane = tid & 63, wv = tid >> 6;
    const int q = blockIdx.y, b = blockIdx.z;

    // ---- stage B slice into LDS: 16384 bf16 = 32 KB, fully coalesced ----
    #pragma unroll
    for (int it = 0; it < 8; ++it) {
        const int idx    = it * 2048 + tid * 8;
        const int c2     = idx / CHE;         // (ti*4 + s)
        const int within = idx % CHE;
        const int s  = c2 & 3, ti = c2 >> 2;
        const int kh = PH ? (ti / NW) * 2 : 1;
        const int kw = PW ? (ti % NW) * 2 : 1;
        const int tap = kh * 3 + kw;
        *(bf16x8*)(bsh + idx) =
            *(const bf16x8*)(wl + ((tap * 4 + s) * 8 + t0) * 512 + within);
    }
    __syncthreads();

    const int rp = wv >> 1, chf = wv & 1;
    const int rw0 = q * 4 + rp * 2;       // class rows rw0, rw0+1 (oh = 2*rw+PH)
    const int n16  = lane & 15;
    const int quad = lane >> 4;
    const int c    = chf * 16 + n16;      // class col (ow = 2*c + PW)

    float bb[NT];
    #pragma unroll
    for (int tt = 0; tt < NT; ++tt) bb[tt] = bias[(t0 + tt) * 16 + n16];

    // A-frag: A[m=n16][k=quad*8+j] = xbf[b, 2s+(quad>>1), ih, iw, (quad&1)*8+j]
    const __hip_bfloat16* xq = xbf + b * 131072 + (quad >> 1) * 16384 + (quad & 1) * 8;

    f32x4 acc[2][NT];
    #pragma unroll
    for (int r = 0; r < 2; ++r)
        #pragma unroll
        for (int tt = 0; tt < NT; ++tt) acc[r][tt] = (f32x4){0.f, 0.f, 0.f, 0.f};

    #pragma unroll
    for (int khi = 0; khi < NH; ++khi) {
        const int dh = PH ? (1 - khi) : 0;
        const int ih0 = rw0 + dh, ih1 = ih0 + 1;
        const bool v0 = (ih0 < 32), v1 = (ih1 < 32);      // wave-uniform
        const int ih0c = v0 ? ih0 : 31, ih1c = v1 ? ih1 : 31;
        #pragma unroll
        for (int kwi = 0; kwi < NW; ++kwi) {
            const int dw = PW ? (1 - kwi) : 0;
            const int iw = c + dw;
            const bool vw = (iw < 32);                    // per-lane
            const int iwc = vw ? iw : 31;
            const int ti = khi * NW + kwi;
            const __hip_bfloat16* a0p = xq + ih0c * 512 + iwc * 16;
            const __hip_bfloat16* a1p = xq + ih1c * 512 + iwc * 16;
            const __hip_bfloat16* wb  = bsh + ti * (4 * CHE) + lane * 8;
            #pragma unroll
            for (int s = 0; s < 4; ++s) {
                bf16x8 a0 = *(const bf16x8*)(a0p + s * 32768);
                bf16x8 a1 = *(const bf16x8*)(a1p + s * 32768);
                if (!(v0 && vw)) a0 = (bf16x8){};
                if (!(v1 && vw)) a1 = (bf16x8){};
                #pragma unroll
                for (int tt = 0; tt < NT; ++tt) {
                    bf16x8 bf = *(const bf16x8*)(wb + s * CHE + tt * 512);
                    acc[0][tt] = __builtin_amdgcn_mfma_f32_16x16x32_bf16(a0, bf, acc[0][tt], 0, 0, 0);
                    acc[1][tt] = __builtin_amdgcn_mfma_f32_16x16x32_bf16(a1, bf, acc[1][tt], 0, 0, 0);
                }
            }
        }
    }

    // Epilogue: +bias, squash over d (16-lane rows) via DPP, nontemporal store.
    // C/D: d = n16, pixel row p = quad*4 + reg -> ow = 2*(chf*16+p) + PW.
    #pragma unroll
    for (int row = 0; row < 2; ++row) {
        const int oh = (rw0 + row) * 2 + PH;
        #pragma unroll
        for (int tt = 0; tt < NT; ++tt) {
            #pragma unroll
            for (int r = 0; r < 4; ++r) {
                const float y  = acc[row][tt][r] + bb[tt];
                const float s2 = rowsum16(y * y);
                const float f  = s2 / ((1.f + s2) * sqrtf(s2 + 1e-7f));
                const int ow = (chf * 16 + quad * 4 + r) * 2 + PW;
                __builtin_nontemporal_store(
                    y * f,
                    out + (((b * 8 + t0 + tt) * 64 + oh) * 64 + ow) * 16 + n16);
            }
        }
    }
}

__global__ __launch_bounds__(256, 4) void caps_mfma(
    const __hip_bfloat16* __restrict__ xbf, const __hip_bfloat16* __restrict__ wl,
    const float* __restrict__ bias, float* __restrict__ out)
{
    __shared__ __hip_bfloat16 bsh[16384];  // 32 KB, uniform across variants
    const int bx = blockIdx.x;             // 9 balanced variants (64 MFMA/wave)
    if      (bx == 0) caps_body<0, 0, 8>(xbf, wl, bias, out, bsh, 0);
    else if (bx <  3) caps_body<0, 1, 4>(xbf, wl, bias, out, bsh, (bx - 1) * 4);
    else if (bx <  5) caps_body<1, 0, 4>(xbf, wl, bias, out, bsh, (bx - 3) * 4);
    else              caps_body<1, 1, 2>(xbf, wl, bias, out, bsh, (bx - 5) * 2);
}

extern "C" void kernel_launch(void* const* d_in, const int* in_sizes, int n_in,
                              void* d_out, int out_size, void* d_ws, size_t ws_size,
                              hipStream_t stream) {
    const float* x    = (const float*)d_in[0];
    const float* wgt  = (const float*)d_in[1];
    const float* bias = (const float*)d_in[2];
    float* out = (float*)d_out;

    __hip_bfloat16* xbf = (__hip_bfloat16*)d_ws;
    __hip_bfloat16* wlb = xbf + XBF_ELEMS;

    prep<<<1024 + 576, 256, 0, stream>>>(x, wgt, xbf, wlb);
    caps_mfma<<<dim3(9, 8, 16), 256, 0, stream>>>(xbf, wlb, bias, out);
}

// Round 8
// 91.292 us; speedup vs baseline: 1.0563x; 1.0187x over previous
//
#include <hip/hip_runtime.h>
#include <hip/hip_bf16.h>
#include <math.h>

// out = squash(ConvTranspose2d(x)+bias); routing loop is identity (R0 analysis).
// GEMM per parity class (ph,pw): out[px,co] = bias + sum_{tap in class} X·W_tap
// bf16 MFMA 16x16x32. Class taps: (0,0)->1, (0,1)/(1,0)->2, (1,1)->4.
//
// R8: (1) zero-padded xbf [16][8][33][33][16] -> no edge masks in K-loop;
// (2) NT<=4 everywhere (class (0,0) split into 2 co-half blocks) so VGPR
// pressure ~90 stays under the launch_bounds(256,4) cap of 128 (spill
// hypothesis for the additive-pipe behavior of R5-R7); (3) tt-outer/s-inner
// K-loop, a-frags hoisted per tap. Grid 10 x 8 x 16 = 1280 = 5 blocks/CU.
//
// ws: [0,4.46MB) xbf bf16 [16][8][33][33][16]  (pad row/col 32 = zeros)
//     [4.5MB,..) Wl  bf16 [9][4][8][64][8] (tap,s,t,lane,j);
//                B[n=lane&15][k=quad*8+j], co=t*16+n, ci=s*32+quad*8+j.

typedef __attribute__((ext_vector_type(8))) __bf16 bf16x8;
typedef __attribute__((ext_vector_type(4))) float f32x4;

#define XPAD_ELEMS (16 * 8 * 33 * 33 * 16)   // 2230272
#define XPAD_B 139392
#define XPAD_MI 17424
#define XPAD_IH 528

__global__ __launch_bounds__(256) void prep(const float* __restrict__ x,
                                            const float* __restrict__ w,
                                            __hip_bfloat16* __restrict__ xbf,
                                            __hip_bfloat16* __restrict__ wl) {
    const int bx = blockIdx.x;
    if (bx < 1089) {  // padded x -> bf16, 8 elems/thread (2230272 = 1089*256*8)
        const int i  = (bx * 256 + threadIdx.x) * 8;
        const int b  = i / XPAD_B;
        const int r1 = i - b * XPAD_B;
        const int mi = r1 / XPAD_MI;
        const int r2 = r1 - mi * XPAD_MI;
        const int ih = r2 / XPAD_IH;
        const int r3 = r2 - ih * XPAD_IH;
        const int iw = r3 >> 4;
        const int di = r3 & 15;   // multiple of 8
        bf16x8 o = {};
        if (ih < 32 && iw < 32) {
            const float* s = x + b * 131072 + mi * 16384 + ih * 512 + iw * 16 + di;
            float4 a = *(const float4*)s;
            float4 c = *(const float4*)(s + 4);
            union { bf16x8 v; __hip_bfloat162 h[4]; } u;
            u.h[0] = __float22bfloat162_rn(make_float2(a.x, a.y));
            u.h[1] = __float22bfloat162_rn(make_float2(a.z, a.w));
            u.h[2] = __float22bfloat162_rn(make_float2(c.x, c.y));
            u.h[3] = __float22bfloat162_rn(make_float2(c.z, c.w));
            o = u.v;
        }
        *(bf16x8*)(xbf + i) = o;
    } else {          // w -> fragment-linear bf16
        const int idx = (bx - 1089) * 256 + threadIdx.x;  // = ci*1152+co*9+tap
        const int ci  = idx / 1152;
        const int rem = idx - ci * 1152;
        const int co  = rem / 9;
        const int tap = rem - co * 9;
        const int s = ci >> 5, quad = (ci >> 3) & 3, j = ci & 7;
        const int t = co >> 4, n16 = co & 15;
        const int dst = ((((tap * 4 + s) * 8 + t) * 64) + quad * 16 + n16) * 8 + j;
        wl[dst] = __float2bfloat16(w[idx]);
    }
}

// DPP butterfly add within each 16-lane row (VALU pipe).
template <int CTRL>
__device__ __forceinline__ float dpp_xadd(float v) {
    int p = __builtin_amdgcn_update_dpp(0, __float_as_int(v), CTRL, 0xF, 0xF, true);
    return v + __int_as_float(p);
}
__device__ __forceinline__ float rowsum16(float v) {
    v = dpp_xadd<0xB1>(v);    // quad_perm xor1
    v = dpp_xadd<0x4E>(v);    // quad_perm xor2
    v = dpp_xadd<0x141>(v);   // row_half_mirror
    v = dpp_xadd<0x140>(v);   // row_mirror
    return v;
}

template <int PH, int PW, int NT>
__device__ __forceinline__ void caps_body(
    const __hip_bfloat16* __restrict__ xbf, const __hip_bfloat16* __restrict__ wl,
    const float* __restrict__ bias, float* __restrict__ out,
    __hip_bfloat16* bsh, int t0)
{
    constexpr int NH = PH ? 2 : 1, NW = PW ? 2 : 1;
    constexpr int NTAP = NH * NW;
    constexpr int CHE  = NT * 512;             // elems per (tap,s) chunk
    constexpr int STG  = NTAP * 4 * CHE;       // staged elems (<= 16384)
    const int tid = threadIdx.x, lane = tid & 63, wv = tid >> 6;
    const int q = blockIdx.y, b = blockIdx.z;

    // ---- stage B slice into LDS, fully coalesced ----
    #pragma unroll
    for (int it = 0; it < STG / 2048; ++it) {
        const int idx    = it * 2048 + tid * 8;
        const int c2     = idx / CHE;          // ti*4 + s
        const int within = idx % CHE;
        const int s  = c2 & 3, ti = c2 >> 2;
        const int kh = PH ? (ti / NW) * 2 : 1;
        const int kw = PW ? (ti % NW) * 2 : 1;
        const int tap = kh * 3 + kw;
        *(bf16x8*)(bsh + idx) =
            *(const bf16x8*)(wl + ((tap * 4 + s) * 8 + t0) * 512 + within);
    }
    __syncthreads();

    const int rp = wv >> 1, chf = wv & 1;
    const int rw0 = q * 4 + rp * 2;        // class rows rw0, rw0+1 (oh = 2*rw+PH)
    const int n16  = lane & 15;
    const int quad = lane >> 4;
    const int c    = chf * 16 + n16;       // class col (ow = 2*c + PW)

    float bb[NT];
    #pragma unroll
    for (int tt = 0; tt < NT; ++tt) bb[tt] = bias[(t0 + tt) * 16 + n16];

    // A-frag: A[m=n16][k=quad*8+j] = xbf[b, 2s+(quad>>1), ih, iw, (quad&1)*8+j]
    const __hip_bfloat16* xq = xbf + b * XPAD_B + (quad >> 1) * XPAD_MI + (quad & 1) * 8;

    f32x4 acc[2][NT];
    #pragma unroll
    for (int r = 0; r < 2; ++r)
        #pragma unroll
        for (int tt = 0; tt < NT; ++tt) acc[r][tt] = (f32x4){0.f, 0.f, 0.f, 0.f};

    #pragma unroll
    for (int khi = 0; khi < NH; ++khi) {
        const int dh  = PH ? (1 - khi) : 0;
        const int ih0 = rw0 + dh;              // <= 32 (padded, zero rows)
        #pragma unroll
        for (int kwi = 0; kwi < NW; ++kwi) {
            const int dw = PW ? (1 - kwi) : 0;
            const int iw = c + dw;             // <= 32 (padded, zero col)
            const int ti = khi * NW + kwi;
            const __hip_bfloat16* ap = xq + ih0 * XPAD_IH + iw * 16;
            const __hip_bfloat16* wb = bsh + ti * (4 * CHE) + lane * 8;
            // hoist A for all 4 s (unconditional — padding handles edges)
            bf16x8 a0[4], a1[4];
            #pragma unroll
            for (int s = 0; s < 4; ++s) {
                a0[s] = *(const bf16x8*)(ap + s * (2 * XPAD_MI));
                a1[s] = *(const bf16x8*)(ap + s * (2 * XPAD_MI) + XPAD_IH);
            }
            #pragma unroll
            for (int tt = 0; tt < NT; ++tt) {
                #pragma unroll
                for (int s = 0; s < 4; ++s) {
                    bf16x8 bf = *(const bf16x8*)(wb + s * CHE + tt * 512);
                    acc[0][tt] = __builtin_amdgcn_mfma_f32_16x16x32_bf16(a0[s], bf, acc[0][tt], 0, 0, 0);
                    acc[1][tt] = __builtin_amdgcn_mfma_f32_16x16x32_bf16(a1[s], bf, acc[1][tt], 0, 0, 0);
                }
            }
        }
    }

    // Epilogue: +bias, squash over d (16-lane rows) via DPP, nontemporal store.
    #pragma unroll
    for (int row = 0; row < 2; ++row) {
        const int oh = (rw0 + row) * 2 + PH;
        #pragma unroll
        for (int tt = 0; tt < NT; ++tt) {
            #pragma unroll
            for (int r = 0; r < 4; ++r) {
                const float y  = acc[row][tt][r] + bb[tt];
                const float s2 = rowsum16(y * y);
                const float f  = s2 / ((1.f + s2) * sqrtf(s2 + 1e-7f));
                const int ow = (chf * 16 + quad * 4 + r) * 2 + PW;
                __builtin_nontemporal_store(
                    y * f,
                    out + (((b * 8 + t0 + tt) * 64 + oh) * 64 + ow) * 16 + n16);
            }
        }
    }
}

__global__ __launch_bounds__(256, 4) void caps_mfma(
    const __hip_bfloat16* __restrict__ xbf, const __hip_bfloat16* __restrict__ wl,
    const float* __restrict__ bias, float* __restrict__ out)
{
    __shared__ __hip_bfloat16 bsh[16384];  // <= 32 KB, uniform
    const int bx = blockIdx.x;             // 10 variants, NT <= 4
    if      (bx <  2) caps_body<0, 0, 4>(xbf, wl, bias, out, bsh, bx * 4);
    else if (bx <  4) caps_body<0, 1, 4>(xbf, wl, bias, out, bsh, (bx - 2) * 4);
    else if (bx <  6) caps_body<1, 0, 4>(xbf, wl, bias, out, bsh, (bx - 4) * 4);
    else              caps_body<1, 1, 2>(xbf, wl, bias, out, bsh, (bx - 6) * 2);
}

extern "C" void kernel_launch(void* const* d_in, const int* in_sizes, int n_in,
                              void* d_out, int out_size, void* d_ws, size_t ws_size,
                              hipStream_t stream) {
    const float* x    = (const float*)d_in[0];
    const float* wgt  = (const float*)d_in[1];
    const float* bias = (const float*)d_in[2];
    float* out = (float*)d_out;

    __hip_bfloat16* xbf = (__hip_bfloat16*)d_ws;
    __hip_bfloat16* wlb = xbf + XPAD_ELEMS;

    prep<<<1089 + 576, 256, 0, stream>>>(x, wgt, xbf, wlb);
    caps_mfma<<<dim3(10, 8, 16), 256, 0, stream>>>(xbf, wlb, bias, out);
}

// Round 9
// 88.106 us; speedup vs baseline: 1.0945x; 1.0362x over previous
//
#include <hip/hip_runtime.h>
#include <hip/hip_bf16.h>
#include <math.h>

// out = squash(ConvTranspose2d(x)+bias); routing loop is identity (R0 analysis).
// GEMM per parity class (ph,pw): out[px,co] = bias + sum_{tap in class} X·W_tap
// bf16 MFMA 16x16x32. Class taps: (0,0)->1, (0,1)/(1,0)->2, (1,1)->4.
//
// R9: (1) __launch_bounds__(256,5): grid is exactly 5 blocks/CU (1280/256);
// with min 4 waves/EU only 4 were resident -> serialized 5th-block tail.
// LDS 5*32KB = 160KB exactly fits; VGPR body ~90 fits the ~102 cap.
// (2) epilogue uses v_rcp/v_rsq approx intrinsics instead of precise
// sqrtf+fdiv (div_scale/fmas/fixup chain) -- threshold headroom is 4.5x.
//
// ws: [0,4.46MB) xbf bf16 [16][8][33][33][16]  (pad row/col 32 = zeros)
//     [4.5MB,..) Wl  bf16 [9][4][8][64][8] (tap,s,t,lane,j);
//                B[n=lane&15][k=quad*8+j], co=t*16+n, ci=s*32+quad*8+j.

typedef __attribute__((ext_vector_type(8))) __bf16 bf16x8;
typedef __attribute__((ext_vector_type(4))) float f32x4;

#define XPAD_ELEMS (16 * 8 * 33 * 33 * 16)   // 2230272
#define XPAD_B 139392
#define XPAD_MI 17424
#define XPAD_IH 528

__global__ __launch_bounds__(256) void prep(const float* __restrict__ x,
                                            const float* __restrict__ w,
                                            __hip_bfloat16* __restrict__ xbf,
                                            __hip_bfloat16* __restrict__ wl) {
    const int bx = blockIdx.x;
    if (bx < 1089) {  // padded x -> bf16, 8 elems/thread (2230272 = 1089*256*8)
        const int i  = (bx * 256 + threadIdx.x) * 8;
        const int b  = i / XPAD_B;
        const int r1 = i - b * XPAD_B;
        const int mi = r1 / XPAD_MI;
        const int r2 = r1 - mi * XPAD_MI;
        const int ih = r2 / XPAD_IH;
        const int r3 = r2 - ih * XPAD_IH;
        const int iw = r3 >> 4;
        const int di = r3 & 15;   // multiple of 8
        bf16x8 o = {};
        if (ih < 32 && iw < 32) {
            const float* s = x + b * 131072 + mi * 16384 + ih * 512 + iw * 16 + di;
            float4 a = *(const float4*)s;
            float4 c = *(const float4*)(s + 4);
            union { bf16x8 v; __hip_bfloat162 h[4]; } u;
            u.h[0] = __float22bfloat162_rn(make_float2(a.x, a.y));
            u.h[1] = __float22bfloat162_rn(make_float2(a.z, a.w));
            u.h[2] = __float22bfloat162_rn(make_float2(c.x, c.y));
            u.h[3] = __float22bfloat162_rn(make_float2(c.z, c.w));
            o = u.v;
        }
        *(bf16x8*)(xbf + i) = o;
    } else {          // w -> fragment-linear bf16
        const int idx = (bx - 1089) * 256 + threadIdx.x;  // = ci*1152+co*9+tap
        const int ci  = idx / 1152;
        const int rem = idx - ci * 1152;
        const int co  = rem / 9;
        const int tap = rem - co * 9;
        const int s = ci >> 5, quad = (ci >> 3) & 3, j = ci & 7;
        const int t = co >> 4, n16 = co & 15;
        const int dst = ((((tap * 4 + s) * 8 + t) * 64) + quad * 16 + n16) * 8 + j;
        wl[dst] = __float2bfloat16(w[idx]);
    }
}

// DPP butterfly add within each 16-lane row (VALU pipe).
template <int CTRL>
__device__ __forceinline__ float dpp_xadd(float v) {
    int p = __builtin_amdgcn_update_dpp(0, __float_as_int(v), CTRL, 0xF, 0xF, true);
    return v + __int_as_float(p);
}
__device__ __forceinline__ float rowsum16(float v) {
    v = dpp_xadd<0xB1>(v);    // quad_perm xor1
    v = dpp_xadd<0x4E>(v);    // quad_perm xor2
    v = dpp_xadd<0x141>(v);   // row_half_mirror
    v = dpp_xadd<0x140>(v);   // row_mirror
    return v;
}

// squash factor: s2/((1+s2)*sqrt(s2+eps)) via HW approx rcp/rsq (1-ulp-ish;
// threshold headroom 4.5x over current bf16 absmax).
__device__ __forceinline__ float squash_f(float s2) {
    return s2 * __builtin_amdgcn_rsqf(s2 + 1e-7f) * __builtin_amdgcn_rcpf(1.f + s2);
}

template <int PH, int PW, int NT>
__device__ __forceinline__ void caps_body(
    const __hip_bfloat16* __restrict__ xbf, const __hip_bfloat16* __restrict__ wl,
    const float* __restrict__ bias, float* __restrict__ out,
    __hip_bfloat16* bsh, int t0)
{
    constexpr int NH = PH ? 2 : 1, NW = PW ? 2 : 1;
    constexpr int NTAP = NH * NW;
    constexpr int CHE  = NT * 512;             // elems per (tap,s) chunk
    constexpr int STG  = NTAP * 4 * CHE;       // staged elems (<= 16384)
    const int tid = threadIdx.x, lane = tid & 63, wv = tid >> 6;
    const int q = blockIdx.y, b = blockIdx.z;

    // ---- stage B slice into LDS, fully coalesced ----
    #pragma unroll
    for (int it = 0; it < STG / 2048; ++it) {
        const int idx    = it * 2048 + tid * 8;
        const int c2     = idx / CHE;          // ti*4 + s
        const int within = idx % CHE;
        const int s  = c2 & 3, ti = c2 >> 2;
        const int kh = PH ? (ti / NW) * 2 : 1;
        const int kw = PW ? (ti % NW) * 2 : 1;
        const int tap = kh * 3 + kw;
        *(bf16x8*)(bsh + idx) =
            *(const bf16x8*)(wl + ((tap * 4 + s) * 8 + t0) * 512 + within);
    }
    __syncthreads();

    const int rp = wv >> 1, chf = wv & 1;
    const int rw0 = q * 4 + rp * 2;        // class rows rw0, rw0+1 (oh = 2*rw+PH)
    const int n16  = lane & 15;
    const int quad = lane >> 4;
    const int c    = chf * 16 + n16;       // class col (ow = 2*c + PW)

    float bb[NT];
    #pragma unroll
    for (int tt = 0; tt < NT; ++tt) bb[tt] = bias[(t0 + tt) * 16 + n16];

    // A-frag: A[m=n16][k=quad*8+j] = xbf[b, 2s+(quad>>1), ih, iw, (quad&1)*8+j]
    const __hip_bfloat16* xq = xbf + b * XPAD_B + (quad >> 1) * XPAD_MI + (quad & 1) * 8;

    f32x4 acc[2][NT];
    #pragma unroll
    for (int r = 0; r < 2; ++r)
        #pragma unroll
        for (int tt = 0; tt < NT; ++tt) acc[r][tt] = (f32x4){0.f, 0.f, 0.f, 0.f};

    #pragma unroll
    for (int khi = 0; khi < NH; ++khi) {
        const int dh  = PH ? (1 - khi) : 0;
        const int ih0 = rw0 + dh;              // <= 32 (padded, zero rows)
        #pragma unroll
        for (int kwi = 0; kwi < NW; ++kwi) {
            const int dw = PW ? (1 - kwi) : 0;
            const int iw = c + dw;             // <= 32 (padded, zero col)
            const int ti = khi * NW + kwi;
            const __hip_bfloat16* ap = xq + ih0 * XPAD_IH + iw * 16;
            const __hip_bfloat16* wb = bsh + ti * (4 * CHE) + lane * 8;
            // hoist A for all 4 s (unconditional — padding handles edges)
            bf16x8 a0[4], a1[4];
            #pragma unroll
            for (int s = 0; s < 4; ++s) {
                a0[s] = *(const bf16x8*)(ap + s * (2 * XPAD_MI));
                a1[s] = *(const bf16x8*)(ap + s * (2 * XPAD_MI) + XPAD_IH);
            }
            #pragma unroll
            for (int tt = 0; tt < NT; ++tt) {
                #pragma unroll
                for (int s = 0; s < 4; ++s) {
                    bf16x8 bf = *(const bf16x8*)(wb + s * CHE + tt * 512);
                    acc[0][tt] = __builtin_amdgcn_mfma_f32_16x16x32_bf16(a0[s], bf, acc[0][tt], 0, 0, 0);
                    acc[1][tt] = __builtin_amdgcn_mfma_f32_16x16x32_bf16(a1[s], bf, acc[1][tt], 0, 0, 0);
                }
            }
        }
    }

    // Epilogue: +bias, squash over d (16-lane rows) via DPP, nontemporal store.
    #pragma unroll
    for (int row = 0; row < 2; ++row) {
        const int oh = (rw0 + row) * 2 + PH;
        #pragma unroll
        for (int tt = 0; tt < NT; ++tt) {
            #pragma unroll
            for (int r = 0; r < 4; ++r) {
                const float y  = acc[row][tt][r] + bb[tt];
                const float f  = squash_f(rowsum16(y * y));
                const int ow = (chf * 16 + quad * 4 + r) * 2 + PW;
                __builtin_nontemporal_store(
                    y * f,
                    out + (((b * 8 + t0 + tt) * 64 + oh) * 64 + ow) * 16 + n16);
            }
        }
    }
}

__global__ __launch_bounds__(256, 5) void caps_mfma(
    const __hip_bfloat16* __restrict__ xbf, const __hip_bfloat16* __restrict__ wl,
    const float* __restrict__ bias, float* __restrict__ out)
{
    __shared__ __hip_bfloat16 bsh[16384];  // 32 KB * 5 blocks = 160 KB/CU exact
    const int bx = blockIdx.x;             // 10 variants, NT <= 4
    if      (bx <  2) caps_body<0, 0, 4>(xbf, wl, bias, out, bsh, bx * 4);
    else if (bx <  4) caps_body<0, 1, 4>(xbf, wl, bias, out, bsh, (bx - 2) * 4);
    else if (bx <  6) caps_body<1, 0, 4>(xbf, wl, bias, out, bsh, (bx - 4) * 4);
    else              caps_body<1, 1, 2>(xbf, wl, bias, out, bsh, (bx - 6) * 2);
}

extern "C" void kernel_launch(void* const* d_in, const int* in_sizes, int n_in,
                              void* d_out, int out_size, void* d_ws, size_t ws_size,
                              hipStream_t stream) {
    const float* x    = (const float*)d_in[0];
    const float* wgt  = (const float*)d_in[1];
    const float* bias = (const float*)d_in[2];
    float* out = (float*)d_out;

    __hip_bfloat16* xbf = (__hip_bfloat16*)d_ws;
    __hip_bfloat16* wlb = xbf + XPAD_ELEMS;

    prep<<<1089 + 576, 256, 0, stream>>>(x, wgt, xbf, wlb);
    caps_mfma<<<dim3(10, 8, 16), 256, 0, stream>>>(xbf, wlb, bias, out);
}

// Round 10
// 88.023 us; speedup vs baseline: 1.0956x; 1.0009x over previous
//
#include <hip/hip_runtime.h>
#include <hip/hip_bf16.h>
#include <math.h>

// out = squash(ConvTranspose2d(x)+bias); routing loop is identity (R0 analysis).
// GEMM per parity class (ph,pw): out[px,co] = bias + sum_{tap in class} X·W_tap
// bf16 MFMA 16x16x32. Class taps: (0,0)->1, (0,1)/(1,0)->2, (1,1)->4.
//
// R10: B staged via __builtin_amdgcn_global_load_lds width=16 (direct
// global->LDS DMA; drops the VGPR round-trip + 32 transient VGPRs at the
// tight 102-VGPR/5-wave budget). Staging layout satisfies the wave-uniform
// base + lane*16B constraint: per wave, src = slice + lane*16B, dst =
// bsh + it*2048 + wv*512 (uniform). Rest frozen from R9.
//
// ws: [0,4.46MB) xbf bf16 [16][8][33][33][16]  (pad row/col 32 = zeros)
//     [4.5MB,..) Wl  bf16 [9][4][8][64][8] (tap,s,t,lane,j);
//                B[n=lane&15][k=quad*8+j], co=t*16+n, ci=s*32+quad*8+j.

typedef __attribute__((ext_vector_type(8))) __bf16 bf16x8;
typedef __attribute__((ext_vector_type(4))) float f32x4;

#define XPAD_ELEMS (16 * 8 * 33 * 33 * 16)   // 2230272
#define XPAD_B 139392
#define XPAD_MI 17424
#define XPAD_IH 528

__global__ __launch_bounds__(256) void prep(const float* __restrict__ x,
                                            const float* __restrict__ w,
                                            __hip_bfloat16* __restrict__ xbf,
                                            __hip_bfloat16* __restrict__ wl) {
    const int bx = blockIdx.x;
    if (bx < 1089) {  // padded x -> bf16, 8 elems/thread (2230272 = 1089*256*8)
        const int i  = (bx * 256 + threadIdx.x) * 8;
        const int b  = i / XPAD_B;
        const int r1 = i - b * XPAD_B;
        const int mi = r1 / XPAD_MI;
        const int r2 = r1 - mi * XPAD_MI;
        const int ih = r2 / XPAD_IH;
        const int r3 = r2 - ih * XPAD_IH;
        const int iw = r3 >> 4;
        const int di = r3 & 15;   // multiple of 8
        bf16x8 o = {};
        if (ih < 32 && iw < 32) {
            const float* s = x + b * 131072 + mi * 16384 + ih * 512 + iw * 16 + di;
            float4 a = *(const float4*)s;
            float4 c = *(const float4*)(s + 4);
            union { bf16x8 v; __hip_bfloat162 h[4]; } u;
            u.h[0] = __float22bfloat162_rn(make_float2(a.x, a.y));
            u.h[1] = __float22bfloat162_rn(make_float2(a.z, a.w));
            u.h[2] = __float22bfloat162_rn(make_float2(c.x, c.y));
            u.h[3] = __float22bfloat162_rn(make_float2(c.z, c.w));
            o = u.v;
        }
        *(bf16x8*)(xbf + i) = o;
    } else {          // w -> fragment-linear bf16
        const int idx = (bx - 1089) * 256 + threadIdx.x;  // = ci*1152+co*9+tap
        const int ci  = idx / 1152;
        const int rem = idx - ci * 1152;
        const int co  = rem / 9;
        const int tap = rem - co * 9;
        const int s = ci >> 5, quad = (ci >> 3) & 3, j = ci & 7;
        const int t = co >> 4, n16 = co & 15;
        const int dst = ((((tap * 4 + s) * 8 + t) * 64) + quad * 16 + n16) * 8 + j;
        wl[dst] = __float2bfloat16(w[idx]);
    }
}

// DPP butterfly add within each 16-lane row (VALU pipe).
template <int CTRL>
__device__ __forceinline__ float dpp_xadd(float v) {
    int p = __builtin_amdgcn_update_dpp(0, __float_as_int(v), CTRL, 0xF, 0xF, true);
    return v + __int_as_float(p);
}
__device__ __forceinline__ float rowsum16(float v) {
    v = dpp_xadd<0xB1>(v);    // quad_perm xor1
    v = dpp_xadd<0x4E>(v);    // quad_perm xor2
    v = dpp_xadd<0x141>(v);   // row_half_mirror
    v = dpp_xadd<0x140>(v);   // row_mirror
    return v;
}

// squash factor via HW approx rcp/rsq (threshold headroom 4.5x).
__device__ __forceinline__ float squash_f(float s2) {
    return s2 * __builtin_amdgcn_rsqf(s2 + 1e-7f) * __builtin_amdgcn_rcpf(1.f + s2);
}

// 16B-per-lane direct global->LDS copy (wave-uniform LDS base + lane*16).
__device__ __forceinline__ void g2l16(const __hip_bfloat16* g, __hip_bfloat16* l) {
    __builtin_amdgcn_global_load_lds(
        (const __attribute__((address_space(1))) unsigned int*)g,
        (__attribute__((address_space(3))) unsigned int*)l,
        16, 0, 0);
}

template <int PH, int PW, int NT>
__device__ __forceinline__ void caps_body(
    const __hip_bfloat16* __restrict__ xbf, const __hip_bfloat16* __restrict__ wl,
    const float* __restrict__ bias, float* __restrict__ out,
    __hip_bfloat16* bsh, int t0)
{
    constexpr int NH = PH ? 2 : 1, NW = PW ? 2 : 1;
    constexpr int NTAP = NH * NW;
    constexpr int CHE  = NT * 512;             // elems per (tap,s) chunk
    constexpr int STG  = NTAP * 4 * CHE;       // staged elems (<= 16384)
    const int tid = threadIdx.x, lane = tid & 63, wv = tid >> 6;
    const int q = blockIdx.y, b = blockIdx.z;

    // ---- stage B slice into LDS via direct DMA ----
    #pragma unroll
    for (int it = 0; it < STG / 2048; ++it) {
        const int ib      = it * 2048 + wv * 512;   // wave-uniform
        const int c2      = ib / CHE;               // ti*4 + s (wave-uniform)
        const int within  = ib % CHE;
        const int s  = c2 & 3, ti = c2 >> 2;
        const int kh = PH ? (ti / NW) * 2 : 1;
        const int kw = PW ? (ti % NW) * 2 : 1;
        const int tap = kh * 3 + kw;
        g2l16(wl + ((tap * 4 + s) * 8 + t0) * 512 + within + lane * 8,
              bsh + ib);
    }
    __syncthreads();

    const int rp = wv >> 1, chf = wv & 1;
    const int rw0 = q * 4 + rp * 2;        // class rows rw0, rw0+1 (oh = 2*rw+PH)
    const int n16  = lane & 15;
    const int quad = lane >> 4;
    const int c    = chf * 16 + n16;       // class col (ow = 2*c + PW)

    float bb[NT];
    #pragma unroll
    for (int tt = 0; tt < NT; ++tt) bb[tt] = bias[(t0 + tt) * 16 + n16];

    // A-frag: A[m=n16][k=quad*8+j] = xbf[b, 2s+(quad>>1), ih, iw, (quad&1)*8+j]
    const __hip_bfloat16* xq = xbf + b * XPAD_B + (quad >> 1) * XPAD_MI + (quad & 1) * 8;

    f32x4 acc[2][NT];
    #pragma unroll
    for (int r = 0; r < 2; ++r)
        #pragma unroll
        for (int tt = 0; tt < NT; ++tt) acc[r][tt] = (f32x4){0.f, 0.f, 0.f, 0.f};

    #pragma unroll
    for (int khi = 0; khi < NH; ++khi) {
        const int dh  = PH ? (1 - khi) : 0;
        const int ih0 = rw0 + dh;              // <= 32 (padded, zero rows)
        #pragma unroll
        for (int kwi = 0; kwi < NW; ++kwi) {
            const int dw = PW ? (1 - kwi) : 0;
            const int iw = c + dw;             // <= 32 (padded, zero col)
            const int ti = khi * NW + kwi;
            const __hip_bfloat16* ap = xq + ih0 * XPAD_IH + iw * 16;
            const __hip_bfloat16* wb = bsh + ti * (4 * CHE) + lane * 8;
            // hoist A for all 4 s (unconditional — padding handles edges)
            bf16x8 a0[4], a1[4];
            #pragma unroll
            for (int s = 0; s < 4; ++s) {
                a0[s] = *(const bf16x8*)(ap + s * (2 * XPAD_MI));
                a1[s] = *(const bf16x8*)(ap + s * (2 * XPAD_MI) + XPAD_IH);
            }
            #pragma unroll
            for (int tt = 0; tt < NT; ++tt) {
                #pragma unroll
                for (int s = 0; s < 4; ++s) {
                    bf16x8 bf = *(const bf16x8*)(wb + s * CHE + tt * 512);
                    acc[0][tt] = __builtin_amdgcn_mfma_f32_16x16x32_bf16(a0[s], bf, acc[0][tt], 0, 0, 0);
                    acc[1][tt] = __builtin_amdgcn_mfma_f32_16x16x32_bf16(a1[s], bf, acc[1][tt], 0, 0, 0);
                }
            }
        }
    }

    // Epilogue: +bias, squash over d (16-lane rows) via DPP, nontemporal store.
    #pragma unroll
    for (int row = 0; row < 2; ++row) {
        const int oh = (rw0 + row) * 2 + PH;
        #pragma unroll
        for (int tt = 0; tt < NT; ++tt) {
            #pragma unroll
            for (int r = 0; r < 4; ++r) {
                const float y  = acc[row][tt][r] + bb[tt];
                const float f  = squash_f(rowsum16(y * y));
                const int ow = (chf * 16 + quad * 4 + r) * 2 + PW;
                __builtin_nontemporal_store(
                    y * f,
                    out + (((b * 8 + t0 + tt) * 64 + oh) * 64 + ow) * 16 + n16);
            }
        }
    }
}

__global__ __launch_bounds__(256, 5) void caps_mfma(
    const __hip_bfloat16* __restrict__ xbf, const __hip_bfloat16* __restrict__ wl,
    const float* __restrict__ bias, float* __restrict__ out)
{
    __shared__ __hip_bfloat16 bsh[16384];  // 32 KB * 5 blocks = 160 KB/CU exact
    const int bx = blockIdx.x;             // 10 variants, NT <= 4
    if      (bx <  2) caps_body<0, 0, 4>(xbf, wl, bias, out, bsh, bx * 4);
    else if (bx <  4) caps_body<0, 1, 4>(xbf, wl, bias, out, bsh, (bx - 2) * 4);
    else if (bx <  6) caps_body<1, 0, 4>(xbf, wl, bias, out, bsh, (bx - 4) * 4);
    else              caps_body<1, 1, 2>(xbf, wl, bias, out, bsh, (bx - 6) * 2);
}

extern "C" void kernel_launch(void* const* d_in, const int* in_sizes, int n_in,
                              void* d_out, int out_size, void* d_ws, size_t ws_size,
                              hipStream_t stream) {
    const float* x    = (const float*)d_in[0];
    const float* wgt  = (const float*)d_in[1];
    const float* bias = (const float*)d_in[2];
    float* out = (float*)d_out;

    __hip_bfloat16* xbf = (__hip_bfloat16*)d_ws;
    __hip_bfloat16* wlb = xbf + XPAD_ELEMS;

    prep<<<1089 + 576, 256, 0, stream>>>(x, wgt, xbf, wlb);
    caps_mfma<<<dim3(10, 8, 16), 256, 0, stream>>>(xbf, wlb, bias, out);
}